// Round 4
// baseline (322.965 us; speedup 1.0000x reference)
//
#include <hip/hip_runtime.h>
#include <math.h>

// RecurNN: B=256, L=256, E=100, T=255.
// x_t = W1L*left_t + W1R*right_t + b1 ; h_t = tanh(x_t); out = sigmoid(W2 h_254 + b2).
// For these inputs: right_t always a leaf; left_t = internal node t-1 (leaf at t=0).
//
// Kernel A (parallel): c[b][t][:] = b1 + (right leaf ? W1R*emb : 0) + (left leaf ? W1L*emb : 0)
//   One WAVE per (b,t) task. Lane l owns rows e=2l,2l+1; W1R packed in 100 float2 VGPRs.
//   emb row read via wave-uniform dwordx4 loads; 100 v_pk_fma_f32; no LDS, no shuffles.
// Kernel B (sequential): per batch row, ONE WAVE, 255 steps:
//   acc = c_t (+ W1L * hist[li-L] if left internal) (+ slow generic right-internal path);
//   h = tanh(acc); hist[t] = h. No barriers, no shuffles. hist = full 255x100 LDS history.

#define Bc 256
#define Lc 256
#define Ec 100
#define Tc 255
#define W1cols 200

// acc.x += wA.x*h ; acc.y += wA.y*h   with h = hp.lo (first) / hp.hi (second, wB)
__device__ __forceinline__ void pkfma2(float2& acc, const float2 wA, const float2 wB, const float2 hp) {
    asm("v_pk_fma_f32 %0, %1, %3, %0 op_sel:[0,0,0] op_sel_hi:[1,0,1]\n\t"
        "v_pk_fma_f32 %0, %2, %3, %0 op_sel:[0,1,0] op_sel_hi:[1,1,1]"
        : "+v"(acc) : "v"(wA), "v"(wB), "v"(hp));
}

// ======================= Phase A =======================
__global__ __launch_bounds__(256, 1)
void phaseA(const int* __restrict__ token_ids,
            const int* __restrict__ comp_left,
            const int* __restrict__ comp_right,
            const float* __restrict__ emb,
            const float* __restrict__ W1,
            const float* __restrict__ b1,
            float* __restrict__ c_ws)
{
    const int lane = threadIdx.x & 63;
    const int wid  = (blockIdx.x << 2) | (threadIdx.x >> 6);
    const int nw   = gridDim.x << 2;
    const int e0 = 2 * lane, e1 = e0 + 1;
    const bool act = (e0 < Ec);

    // W1R rows e0,e1 packed: wpk[k] = {W1R[e0][k], W1R[e1][k]}
    float2 wpk[Ec];
    float2 bini = make_float2(0.f, 0.f);
    if (act) {
        #pragma unroll
        for (int q = 0; q < 25; ++q) {
            float4 a4 = *(const float4*)(W1 + (size_t)e0 * W1cols + Ec + 4 * q);
            float4 b4 = *(const float4*)(W1 + (size_t)e1 * W1cols + Ec + 4 * q);
            wpk[4*q+0] = make_float2(a4.x, b4.x);
            wpk[4*q+1] = make_float2(a4.y, b4.y);
            wpk[4*q+2] = make_float2(a4.z, b4.z);
            wpk[4*q+3] = make_float2(a4.w, b4.w);
        }
        bini = make_float2(b1[e0], b1[e1]);
    } else {
        #pragma unroll
        for (int q = 0; q < Ec; ++q) wpk[q] = make_float2(0.f, 0.f);
    }

    for (int task = wid; task < Bc * Tc; task += nw) {
        const int b = task / Tc;
        const int t = task - b * Tc;
        const int ri = __builtin_amdgcn_readfirstlane(comp_right[b * Tc + t]);
        const int li = __builtin_amdgcn_readfirstlane(comp_left [b * Tc + t]);
        float2 acc = bini;

        if (ri < Lc) {   // right leaf (always, for these inputs)
            const int tok = __builtin_amdgcn_readfirstlane(token_ids[b * Lc + ri]);
            const float* rp = emb + (size_t)tok * Ec;
            #pragma unroll
            for (int q = 0; q < 25; ++q) {
                float4 h4 = *(const float4*)(rp + 4 * q);
                const float2* hp = reinterpret_cast<const float2*>(&h4);
                pkfma2(acc, wpk[4*q+0], wpk[4*q+1], hp[0]);
                pkfma2(acc, wpk[4*q+2], wpk[4*q+3], hp[1]);
            }
        }
        if (li < Lc) {   // left leaf (t==0 only, for these inputs) — W1L from global
            const int tok = __builtin_amdgcn_readfirstlane(token_ids[b * Lc + li]);
            const float* rp = emb + (size_t)tok * Ec;
            if (act) {
                for (int q = 0; q < 25; ++q) {
                    float4 h4 = *(const float4*)(rp + 4 * q);
                    float4 wa = *(const float4*)(W1 + (size_t)e0 * W1cols + 4 * q);
                    float4 wb = *(const float4*)(W1 + (size_t)e1 * W1cols + 4 * q);
                    acc.x = fmaf(wa.x, h4.x, acc.x); acc.x = fmaf(wa.y, h4.y, acc.x);
                    acc.x = fmaf(wa.z, h4.z, acc.x); acc.x = fmaf(wa.w, h4.w, acc.x);
                    acc.y = fmaf(wb.x, h4.x, acc.y); acc.y = fmaf(wb.y, h4.y, acc.y);
                    acc.y = fmaf(wb.z, h4.z, acc.y); acc.y = fmaf(wb.w, h4.w, acc.y);
                }
            }
        }
        if (act)
            *(float2*)(c_ws + ((size_t)b * Tc + t) * Ec + e0) = acc;
    }
}

// ======================= Phase B =======================
__global__ __launch_bounds__(64, 1)
void phaseB(const int* __restrict__ comp_left,
            const int* __restrict__ comp_right,
            const float* __restrict__ W1,
            const float* __restrict__ W2,
            const float* __restrict__ b2,
            const float* __restrict__ c_ws,
            float* __restrict__ out)
{
    const int b = blockIdx.x;
    const int lane = threadIdx.x;          // 0..63
    const int e0 = 2 * lane, e1 = e0 + 1;
    const bool act = (e0 < Ec);

    __shared__ __align__(16) float hist[Tc * Ec];   // 102000 B, full node history
    __shared__ int cliS[Tc], criS[Tc];

    for (int i = lane; i < Tc; i += 64) { cliS[i] = comp_left[b * Tc + i]; criS[i] = comp_right[b * Tc + i]; }
    {
        const float4 z4 = make_float4(0.f, 0.f, 0.f, 0.f);
        for (int i = 4 * lane; i < Tc * Ec; i += 256) *(float4*)&hist[i] = z4;
    }

    // W1L rows e0,e1 packed
    float2 wpk[Ec];
    if (act) {
        #pragma unroll
        for (int q = 0; q < 25; ++q) {
            float4 a4 = *(const float4*)(W1 + (size_t)e0 * W1cols + 4 * q);
            float4 b4 = *(const float4*)(W1 + (size_t)e1 * W1cols + 4 * q);
            wpk[4*q+0] = make_float2(a4.x, b4.x);
            wpk[4*q+1] = make_float2(a4.y, b4.y);
            wpk[4*q+2] = make_float2(a4.z, b4.z);
            wpk[4*q+3] = make_float2(a4.w, b4.w);
        }
    } else {
        #pragma unroll
        for (int q = 0; q < Ec; ++q) wpk[q] = make_float2(0.f, 0.f);
    }
    const float2 w2p = act ? make_float2(W2[e0], W2[e1]) : make_float2(0.f, 0.f);

    const float* cb = c_ws + (size_t)b * Tc * Ec;
    float2 ccur = act ? *(const float2*)(cb + e0) : make_float2(0.f, 0.f);   // c_0
    __syncthreads();   // LDS init visible (single wave: cheap)

    float2 h = make_float2(0.f, 0.f);
    #pragma unroll 1
    for (int t = 0; t < Tc; ++t) {
        // prefetch next step's c (recurrence-independent)
        const int tn = (t + 1 < Tc) ? t + 1 : t;
        float2 cnext = act ? *(const float2*)(cb + (size_t)tn * Ec + e0) : make_float2(0.f, 0.f);

        const int li = __builtin_amdgcn_readfirstlane(cliS[t]);
        const int ri = __builtin_amdgcn_readfirstlane(criS[t]);
        float2 acc = ccur;

        if (li >= Lc) {                        // left internal (general n < t)
            const float* rp = &hist[(li - Lc) * Ec];
            #pragma unroll
            for (int q = 0; q < 25; ++q) {
                float4 h4 = *(const float4*)(rp + 4 * q);   // wave-uniform broadcast
                const float2* hp = reinterpret_cast<const float2*>(&h4);
                pkfma2(acc, wpk[4*q+0], wpk[4*q+1], hp[0]);
                pkfma2(acc, wpk[4*q+2], wpk[4*q+3], hp[1]);
            }
        }
        if (ri >= Lc) {                        // right internal: generic slow path (unused here)
            const float* rp = &hist[(ri - Lc) * Ec];
            if (act) {
                for (int q = 0; q < 25; ++q) {
                    float4 h4 = *(const float4*)(rp + 4 * q);
                    float4 wa = *(const float4*)(W1 + (size_t)e0 * W1cols + Ec + 4 * q);
                    float4 wb = *(const float4*)(W1 + (size_t)e1 * W1cols + Ec + 4 * q);
                    acc.x = fmaf(wa.x, h4.x, acc.x); acc.x = fmaf(wa.y, h4.y, acc.x);
                    acc.x = fmaf(wa.z, h4.z, acc.x); acc.x = fmaf(wa.w, h4.w, acc.x);
                    acc.y = fmaf(wb.x, h4.x, acc.y); acc.y = fmaf(wb.y, h4.y, acc.y);
                    acc.y = fmaf(wb.z, h4.z, acc.y); acc.y = fmaf(wb.w, h4.w, acc.y);
                }
            }
        }

        // h = tanh(acc)  (exact identity via exp)
        const float ux = __expf(2.f * acc.x);
        const float uy = __expf(2.f * acc.y);
        h.x = 1.f - 2.f / (ux + 1.f);
        h.y = 1.f - 2.f / (uy + 1.f);
        if (act) *(float2*)&hist[t * Ec + e0] = h;
        ccur = cnext;
        // no barrier: single wave; compiler orders ds_write -> next ds_read via lgkmcnt
    }

    // out[b] = sigmoid(W2 . h_254 + b2)
    float s = act ? (w2p.x * h.x + w2p.y * h.y) : 0.f;
    #pragma unroll
    for (int off = 1; off < 64; off <<= 1) s += __shfl_xor(s, off, 64);
    if (lane == 0) out[b] = 1.f / (1.f + __expf(-(s + b2[0])));
}

extern "C" void kernel_launch(void* const* d_in, const int* in_sizes, int n_in,
                              void* d_out, int out_size, void* d_ws, size_t ws_size,
                              hipStream_t stream) {
    const int*   token_ids  = (const int*)  d_in[0];
    const int*   comp_left  = (const int*)  d_in[1];
    const int*   comp_right = (const int*)  d_in[2];
    const float* emb        = (const float*)d_in[3];
    const float* W1         = (const float*)d_in[4];
    const float* b1         = (const float*)d_in[5];
    const float* W2         = (const float*)d_in[6];
    const float* b2         = (const float*)d_in[7];
    float*       out        = (float*)d_out;
    float*       c_ws       = (float*)d_ws;       // needs B*T*E*4 = 26,112,000 B

    phaseA<<<512, 256, 0, stream>>>(token_ids, comp_left, comp_right, emb, W1, b1, c_ws);
    phaseB<<<Bc, 64, 0, stream>>>(comp_left, comp_right, W1, W2, b2, c_ws, out);
}